// Round 3
// baseline (163.721 us; speedup 1.0000x reference)
//
#include <hip/hip_runtime.h>
#include <cmath>

#define BLOCK 256

// ---------------------------------------------------------------------------
// Precompute per-(b,k) GT box constants: {x1,y1,x2,y2,area} padded to 8 floats
// (32B stride keeps s_load-friendly alignment). Same arithmetic as reference.
// ---------------------------------------------------------------------------
__global__ void ainno_pre(const float* __restrict__ gt, float* __restrict__ table,
                          int BK) {
    int i = blockIdx.x * blockDim.x + threadIdx.x;
    if (i < BK) {
        float4 g = ((const float4*)gt)[i];
        float x2 = g.x + g.z, y2 = g.y + g.w;
        float* t = table + (size_t)i * 8;
        t[0] = g.x; t[1] = g.y; t[2] = x2; t[3] = y2;
        t[4] = (x2 - g.x) * (y2 - g.y);
        t[5] = 0.f; t[6] = 0.f; t[7] = 0.f;
    }
}

// acc layout: per batch b, 4 floats [pos_count, stc_sum, str_sum, pad];
// acc[4*B] (as int) is the block-completion counter. Zeroed by memsetAsync.
__global__ void __launch_bounds__(BLOCK) ainno_main(
    const float* __restrict__ ss,       // (B, A, 6)
    const float* __restrict__ anchors,  // (A, 4) xywh
    const float* __restrict__ table,    // (B, K, 8) precomputed
    float* __restrict__ acc,
    float* __restrict__ out,
    int A, int K, int B)
{
    __shared__ float red[(BLOCK / 64) * 3];
    const int b    = blockIdx.y;
    const int tid  = threadIdx.x;
    const int lane = tid & 63;
    const int a    = blockIdx.x * BLOCK + tid;
    const int ac   = a < A ? a : A - 1;          // clamp; contribution guarded

    // Prefetch the logit early so its HBM/L2 latency overlaps the k-loop.
    const float* sp = ss + ((size_t)b * A + ac) * 6;
    float logit = sp[4];

    float4 an = ((const float4*)anchors)[ac];
    float ax  = an.x,        ay  = an.y;
    float axx = an.x + an.z, ayy = an.y + an.w;
    float aar = (axx - ax) * (ayy - ay);

    // Uniform (per-block) pointer; k is a uniform induction var -> the box
    // constants are wave-uniform loads (scalar path / L1 broadcast).
    const float* __restrict__ tb = table + (size_t)b * K * 8;

    // Cross-multiplied argmax: one divide total, after the loop, with the
    // exact operands the reference divides -> bit-identical winning IoU.
    float bi = -1.f, bd = 1.f;
    int bk = 0;
    #pragma unroll 8
    for (int k = 0; k < 64; ++k) {
        float sx1 = tb[8 * k + 0];
        float sy1 = tb[8 * k + 1];
        float sx2 = tb[8 * k + 2];
        float sy2 = tb[8 * k + 3];
        float sar = tb[8 * k + 4];
        float w = fminf(axx, sx2) - fmaxf(ax, sx1);
        float h = fminf(ayy, sy2) - fmaxf(ay, sy1);
        w = fmaxf(w, 0.f); h = fmaxf(h, 0.f);
        float inter = w * h;
        float den = aar + sar - inter;
        bool better = inter * bd > bi * den;   // strict > keeps first max (ref argmax)
        bi = better ? inter : bi;
        bd = better ? den   : bd;
        bk = better ? k     : bk;
    }

    float posf = 0.f, stcs = 0.f, strs = 0.f;
    {
        float score = bi / bd;                 // == ref max IoU (same operands)
        bool inb = a < A;
        bool pos = inb && (score >= 0.5f);
        bool neg = inb && (score < 0.4f);
        if (pos | neg) {
            float x = logit;
            float e = expf(-x);
            float p = 1.f / (1.f + e);
            if (pos) {
                posf = 1.f;
                float ce  = log1pf(e);         // softplus(-x) = -log_sigmoid(x)
                float omp = 1.f - p;
                stcs = 0.25f * ce * omp * omp;

                // winning GT box: small-table L1 load (divergent index, rare path)
                const float* tw = tb + (size_t)bk * 8;
                float bx1 = tw[0], by1 = tw[1], bx2 = tw[2], by2 = tw[3], bar = tw[4];

                float2 p01 = *(const float2*)(sp);
                float2 p23 = *(const float2*)(sp + 2);
                float px  = p01.x, py = p01.y;
                float pxx = px + p23.x, pyy = py + p23.y;
                float ew = fminf(pxx, bx2) - fmaxf(px, bx1);
                float eh = fminf(pyy, by2) - fmaxf(py, by1);
                ew = fmaxf(ew, 0.f); eh = fmaxf(eh, 0.f);
                float einter = ew * eh;
                float pa = (pxx - px) * (pyy - py);
                float eiou = einter / (pa + bar - einter);
                strs = -logf(eiou + 0.01f);
            } else {
                float ce = log1pf(expf(x));    // softplus(x) = -log_sigmoid(-x)
                stcs = 0.75f * ce * p * p;
            }
        }
    }

    // wave64 shuffle reduction -> LDS across waves -> 3 atomics per block
    float v0 = posf, v1 = stcs, v2 = strs;
    for (int off = 32; off > 0; off >>= 1) {
        v0 += __shfl_down(v0, off, 64);
        v1 += __shfl_down(v1, off, 64);
        v2 += __shfl_down(v2, off, 64);
    }
    const int wave = tid >> 6;
    if (lane == 0) {
        red[wave * 3 + 0] = v0;
        red[wave * 3 + 1] = v1;
        red[wave * 3 + 2] = v2;
    }
    __syncthreads();
    if (tid == 0) {
        float s0 = 0.f, s1 = 0.f, s2 = 0.f;
        for (int w = 0; w < BLOCK / 64; ++w) {
            s0 += red[w * 3 + 0];
            s1 += red[w * 3 + 1];
            s2 += red[w * 3 + 2];
        }
        atomicAdd(&acc[b * 4 + 0], s0);
        atomicAdd(&acc[b * 4 + 1], s1);
        atomicAdd(&acc[b * 4 + 2], s2);
        __threadfence();
        int total = gridDim.x * gridDim.y;
        int old = atomicAdd((int*)(acc + 4 * B), 1);
        if (old == total - 1) {
            // last block finalizes; device-scope atomic reads avoid stale
            // per-XCD L2 lines
            float tot = 0.f;
            for (int bb = 0; bb < B; ++bb) {
                float pc = atomicAdd(&acc[bb * 4 + 0], 0.f);
                float st = atomicAdd(&acc[bb * 4 + 1], 0.f);
                float sr = atomicAdd(&acc[bb * 4 + 2], 0.f);
                float safe = pc > 0.f ? pc : 1.f;
                tot += st / safe;
                if (pc > 0.f) tot += sr / safe;
            }
            out[0] = tot / (float)B;
        }
    }
}

extern "C" void kernel_launch(void* const* d_in, const int* in_sizes, int n_in,
                              void* d_out, int out_size, void* d_ws, size_t ws_size,
                              hipStream_t stream) {
    const float* ss      = (const float*)d_in[0];
    const float* anchors = (const float*)d_in[1];
    const float* gt      = (const float*)d_in[2];
    float* out = (float*)d_out;
    float* acc = (float*)d_ws;                       // B*4+1 floats
    const int A = in_sizes[1] / 4;
    const int B = in_sizes[0] / (A * 6);
    const int K = in_sizes[2] / (B * 4);
    float* table = acc + (size_t)B * 4 + 4;          // (B*K*8 floats), 16B-aligned

    hipMemsetAsync(acc, 0, ((size_t)B * 4 + 1) * sizeof(float), stream);

    const int BK = B * K;
    ainno_pre<<<(BK + 255) / 256, 256, 0, stream>>>(gt, table, BK);

    dim3 grid((A + BLOCK - 1) / BLOCK, B);
    ainno_main<<<grid, BLOCK, 0, stream>>>(ss, anchors, table, acc, out, A, K, B);
}

// Round 4
// 153.233 us; speedup vs baseline: 1.0684x; 1.0684x over previous
//
#include <hip/hip_runtime.h>
#include <cmath>

#define BLOCK 256

// wave_ror:1 — rotate all 64 lanes by one (CDNA keeps gfx9 wave-level DPP)
__device__ __forceinline__ float rot1_f(float v) {
    return __builtin_bit_cast(float, __builtin_amdgcn_mov_dpp(
        __builtin_bit_cast(int, v), 0x13C, 0xF, 0xF, false));
}
__device__ __forceinline__ int rot1_i(int v) {
    return __builtin_amdgcn_mov_dpp(v, 0x13C, 0xF, 0xF, false);
}

// acc layout: per batch b, 4 floats [pos_count, stc_sum, str_sum, pad];
// acc[4*B] (as int) is the block-completion counter. Zeroed by memsetAsync.
__global__ void __launch_bounds__(BLOCK) ainno_main(
    const float* __restrict__ ss,       // (B, A, 6)
    const float* __restrict__ anchors,  // (A, 4) xywh
    const float* __restrict__ gt,       // (B, K, 4) xywh
    float* __restrict__ acc,
    float* __restrict__ out,
    int A, int K, int B)
{
    __shared__ float red[(BLOCK / 64) * 3];
    const int b    = blockIdx.y;
    const int tid  = threadIdx.x;
    const int lane = tid & 63;
    const int a    = blockIdx.x * BLOCK + tid;
    const int ac   = a < A ? a : A - 1;          // clamp; contribution guarded

    // Prefetch the logit before the k-loop: its HBM latency hides under
    // ~3000 cycles of pure-VALU work.
    const float* sp = ss + ((size_t)b * A + ac) * 6;
    float logit = sp[4];

    // Lane k holds GT box k (K == 64 == wave size). Same arithmetic as ref.
    float bx1, by1, bx2, by2, bar;
    int   bidx = lane;
    {
        int kl = lane < K ? lane : K - 1;        // K==64 here; clamp for safety
        float4 g = ((const float4*)(gt + (size_t)b * K * 4))[kl];
        bx1 = g.x; by1 = g.y; bx2 = g.x + g.z; by2 = g.y + g.w;
        bar = (bx2 - bx1) * (by2 - by1);
    }

    float4 an = ((const float4*)anchors)[ac];
    float ax  = an.x,        ay  = an.y;
    float axx = an.x + an.z, ayy = an.y + an.w;
    float aar = (axx - ax) * (ayy - ay);

    // Systolic argmax: each step computes IoU vs the resident box, then
    // rotates box regs + index reg one lane. Pure VALU — no memory, no
    // SGPR hazards. Cross-multiplied compare: one divide total, after the
    // loop, with the exact operands the reference divides.
    float bi = -1.f, bd = 1.f;
    int bk = 0;
    #pragma unroll
    for (int r = 0; r < 64; ++r) {
        float w = fminf(axx, bx2) - fmaxf(ax, bx1);
        float h = fminf(ayy, by2) - fmaxf(ay, by1);
        w = fmaxf(w, 0.f); h = fmaxf(h, 0.f);
        float inter = w * h;
        float den = (aar + bar) - inter;
        bool better = inter * bd > bi * den;
        bi = better ? inter : bi;
        bd = better ? den   : bd;
        bk = better ? bidx  : bk;
        bx1 = rot1_f(bx1); by1 = rot1_f(by1);
        bx2 = rot1_f(bx2); by2 = rot1_f(by2);
        bar = rot1_f(bar); bidx = rot1_i(bidx);
    }

    float posf = 0.f, stcs = 0.f, strs = 0.f;
    {
        float score = bi / bd;                   // == ref max IoU (same operands)
        bool inb = a < A;
        bool pos = inb && (score >= 0.5f);
        bool neg = inb && (score < 0.4f);
        if (pos | neg) {
            float x = logit;
            float e = expf(-x);
            float p = 1.f / (1.f + e);
            if (pos) {
                posf = 1.f;
                float ce  = log1pf(e);           // softplus(-x) = -log_sigmoid(x)
                float omp = 1.f - p;
                stcs = 0.25f * ce * omp * omp;

                // rare path: reload winning GT box (L1/L2 hit, 1 KB table)
                float4 g = ((const float4*)(gt + (size_t)b * K * 4))[bk];
                float wx1 = g.x, wy1 = g.y;
                float wx2 = g.x + g.z, wy2 = g.y + g.w;
                float war = (wx2 - wx1) * (wy2 - wy1);

                float2 p01 = *(const float2*)(sp);
                float2 p23 = *(const float2*)(sp + 2);
                float px  = p01.x, py = p01.y;
                float pxx = px + p23.x, pyy = py + p23.y;
                float ew = fminf(pxx, wx2) - fmaxf(px, wx1);
                float eh = fminf(pyy, wy2) - fmaxf(py, wy1);
                ew = fmaxf(ew, 0.f); eh = fmaxf(eh, 0.f);
                float einter = ew * eh;
                float pa = (pxx - px) * (pyy - py);
                float eiou = einter / (pa + war - einter);
                strs = -logf(eiou + 0.01f);
            } else {
                float ce = log1pf(expf(x));      // softplus(x) = -log_sigmoid(-x)
                stcs = 0.75f * ce * p * p;
            }
        }
    }

    // wave64 shuffle reduction -> LDS across waves -> 3 atomics per block
    float v0 = posf, v1 = stcs, v2 = strs;
    for (int off = 32; off > 0; off >>= 1) {
        v0 += __shfl_down(v0, off, 64);
        v1 += __shfl_down(v1, off, 64);
        v2 += __shfl_down(v2, off, 64);
    }
    const int wave = tid >> 6;
    if (lane == 0) {
        red[wave * 3 + 0] = v0;
        red[wave * 3 + 1] = v1;
        red[wave * 3 + 2] = v2;
    }
    __syncthreads();
    if (tid == 0) {
        float s0 = 0.f, s1 = 0.f, s2 = 0.f;
        for (int w = 0; w < BLOCK / 64; ++w) {
            s0 += red[w * 3 + 0];
            s1 += red[w * 3 + 1];
            s2 += red[w * 3 + 2];
        }
        atomicAdd(&acc[b * 4 + 0], s0);
        atomicAdd(&acc[b * 4 + 1], s1);
        atomicAdd(&acc[b * 4 + 2], s2);
        __threadfence();
        int total = gridDim.x * gridDim.y;
        int old = atomicAdd((int*)(acc + 4 * B), 1);
        if (old == total - 1) {
            // last block finalizes; device-scope atomic reads avoid stale
            // per-XCD L2 lines
            float tot = 0.f;
            for (int bb = 0; bb < B; ++bb) {
                float pc = atomicAdd(&acc[bb * 4 + 0], 0.f);
                float st = atomicAdd(&acc[bb * 4 + 1], 0.f);
                float sr = atomicAdd(&acc[bb * 4 + 2], 0.f);
                float safe = pc > 0.f ? pc : 1.f;
                tot += st / safe;
                if (pc > 0.f) tot += sr / safe;
            }
            out[0] = tot / (float)B;
        }
    }
}

extern "C" void kernel_launch(void* const* d_in, const int* in_sizes, int n_in,
                              void* d_out, int out_size, void* d_ws, size_t ws_size,
                              hipStream_t stream) {
    const float* ss      = (const float*)d_in[0];
    const float* anchors = (const float*)d_in[1];
    const float* gt      = (const float*)d_in[2];
    float* out = (float*)d_out;
    float* acc = (float*)d_ws;
    const int A = in_sizes[1] / 4;
    const int B = in_sizes[0] / (A * 6);
    const int K = in_sizes[2] / (B * 4);

    hipMemsetAsync(acc, 0, ((size_t)B * 4 + 1) * sizeof(float), stream);

    dim3 grid((A + BLOCK - 1) / BLOCK, B);
    ainno_main<<<grid, BLOCK, 0, stream>>>(ss, anchors, gt, acc, out, A, K, B);
}

// Round 5
// 152.027 us; speedup vs baseline: 1.0769x; 1.0079x over previous
//
#include <hip/hip_runtime.h>
#include <cmath>

#define BLOCK 256

// acc layout: per batch b, 4 floats [pos_count, stc_sum, str_sum, pad];
// acc[4*B] (as int) is the block-completion counter. Zeroed by memsetAsync.
__global__ void __launch_bounds__(BLOCK) ainno_main(
    const float* __restrict__ ss,       // (B, A, 6)
    const float* __restrict__ anchors,  // (A, 4) xywh
    const float* __restrict__ gt,       // (B, K, 4) xywh
    float* __restrict__ acc,
    float* __restrict__ out,
    int A, int K, int B)
{
    // Boxes staged once; hot loop reads them with WAVE-UNIFORM addresses ->
    // LDS broadcast, conflict-free, 1 ds_read_b128 per box.
    __shared__ float4 gbox[64];                    // xyxy
    __shared__ __align__(16) float gar[64];        // area
    __shared__ float red[(BLOCK / 64) * 3];

    const int b    = blockIdx.y;
    const int tid  = threadIdx.x;
    const int lane = tid & 63;
    const int a    = blockIdx.x * BLOCK + tid;
    const int ac   = a < A ? a : A - 1;            // clamp; contribution guarded

    // Stage GT boxes (same arithmetic as reference: x2=x+w, area=(x2-x)*(y2-y)).
    if (tid < 64) {
        if (tid < K) {
            float4 g = ((const float4*)(gt + (size_t)b * K * 4))[tid];
            float x2 = g.x + g.z, y2 = g.y + g.w;
            gbox[tid] = make_float4(g.x, g.y, x2, y2);
            gar[tid]  = (x2 - g.x) * (y2 - g.y);
        } else {
            gbox[tid] = make_float4(0.f, 0.f, 0.f, 0.f);  // never wins argmax
            gar[tid]  = 0.f;
        }
    }

    // Prefetch anchor + logit before the barrier so their HBM latency
    // overlaps the staging sync.
    const float* sp = ss + ((size_t)b * A + ac) * 6;
    float logit = sp[4];
    float4 an = ((const float4*)anchors)[ac];
    float ax  = an.x,        ay  = an.y;
    float axx = an.x + an.z, ayy = an.y + an.w;
    float aar = (axx - ax) * (ayy - ay);

    __syncthreads();

    // Cross-multiplied linear argmax (strict > keeps first max, matching
    // jnp.argmax). One divide total, after the loop, with the exact operands
    // the reference divides -> bit-identical winning IoU.
    float bi = -1.f, bd = 1.f;
    int bk = 0;
    const float4* ga4 = (const float4*)gar;
    #pragma unroll
    for (int kc = 0; kc < 64; kc += 4) {
        // 5 batched broadcast loads per 4 boxes; full unroll lets the
        // compiler keep several chunks in flight (fine-grained lgkmcnt).
        float4 b0 = gbox[kc + 0];
        float4 b1 = gbox[kc + 1];
        float4 b2 = gbox[kc + 2];
        float4 b3 = gbox[kc + 3];
        float4 ar = ga4[kc >> 2];
        #pragma unroll
        for (int j = 0; j < 4; ++j) {
            float4 g  = j == 0 ? b0 : j == 1 ? b1 : j == 2 ? b2 : b3;
            float sar = j == 0 ? ar.x : j == 1 ? ar.y : j == 2 ? ar.z : ar.w;
            float w = fminf(axx, g.z) - fmaxf(ax, g.x);
            float h = fminf(ayy, g.w) - fmaxf(ay, g.y);
            w = fmaxf(w, 0.f); h = fmaxf(h, 0.f);
            float inter = w * h;
            float den = (aar + sar) - inter;
            bool better = inter * bd > bi * den;
            bi = better ? inter : bi;
            bd = better ? den   : bd;
            bk = better ? (kc + j) : bk;
        }
    }

    float posf = 0.f, stcs = 0.f, strs = 0.f;
    {
        float score = bi / bd;                     // == ref max IoU (same operands)
        bool inb = a < A;
        bool pos = inb && (score >= 0.5f);
        bool neg = inb && (score < 0.4f);
        if (pos | neg) {
            float x = logit;
            float e = expf(-x);
            float p = 1.f / (1.f + e);
            if (pos) {
                posf = 1.f;
                float ce  = log1pf(e);             // softplus(-x) = -log_sigmoid(x)
                float omp = 1.f - p;
                stcs = 0.25f * ce * omp * omp;

                // rare path: winner box from LDS (divergent index)
                float4 g  = gbox[bk];
                float war = gar[bk];
                float2 p01 = *(const float2*)(sp);
                float2 p23 = *(const float2*)(sp + 2);
                float px  = p01.x, py = p01.y;
                float pxx = px + p23.x, pyy = py + p23.y;
                float ew = fminf(pxx, g.z) - fmaxf(px, g.x);
                float eh = fminf(pyy, g.w) - fmaxf(py, g.y);
                ew = fmaxf(ew, 0.f); eh = fmaxf(eh, 0.f);
                float einter = ew * eh;
                float pa = (pxx - px) * (pyy - py);
                float eiou = einter / (pa + war - einter);
                strs = -logf(eiou + 0.01f);
            } else {
                float ce = log1pf(expf(x));        // softplus(x) = -log_sigmoid(-x)
                stcs = 0.75f * ce * p * p;
            }
        }
    }

    // wave64 shuffle reduction -> LDS across waves -> 3 atomics per block
    float v0 = posf, v1 = stcs, v2 = strs;
    for (int off = 32; off > 0; off >>= 1) {
        v0 += __shfl_down(v0, off, 64);
        v1 += __shfl_down(v1, off, 64);
        v2 += __shfl_down(v2, off, 64);
    }
    const int wave = tid >> 6;
    if (lane == 0) {
        red[wave * 3 + 0] = v0;
        red[wave * 3 + 1] = v1;
        red[wave * 3 + 2] = v2;
    }
    __syncthreads();
    if (tid == 0) {
        float s0 = 0.f, s1 = 0.f, s2 = 0.f;
        for (int w = 0; w < BLOCK / 64; ++w) {
            s0 += red[w * 3 + 0];
            s1 += red[w * 3 + 1];
            s2 += red[w * 3 + 2];
        }
        atomicAdd(&acc[b * 4 + 0], s0);
        atomicAdd(&acc[b * 4 + 1], s1);
        atomicAdd(&acc[b * 4 + 2], s2);
        __threadfence();
        int total = gridDim.x * gridDim.y;
        int old = atomicAdd((int*)(acc + 4 * B), 1);
        if (old == total - 1) {
            // last block finalizes; device-scope atomic reads avoid stale
            // per-XCD L2 lines
            float tot = 0.f;
            for (int bb = 0; bb < B; ++bb) {
                float pc = atomicAdd(&acc[bb * 4 + 0], 0.f);
                float st = atomicAdd(&acc[bb * 4 + 1], 0.f);
                float sr = atomicAdd(&acc[bb * 4 + 2], 0.f);
                float safe = pc > 0.f ? pc : 1.f;
                tot += st / safe;
                if (pc > 0.f) tot += sr / safe;
            }
            out[0] = tot / (float)B;
        }
    }
}

extern "C" void kernel_launch(void* const* d_in, const int* in_sizes, int n_in,
                              void* d_out, int out_size, void* d_ws, size_t ws_size,
                              hipStream_t stream) {
    const float* ss      = (const float*)d_in[0];
    const float* anchors = (const float*)d_in[1];
    const float* gt      = (const float*)d_in[2];
    float* out = (float*)d_out;
    float* acc = (float*)d_ws;
    const int A = in_sizes[1] / 4;
    const int B = in_sizes[0] / (A * 6);
    const int K = in_sizes[2] / (B * 4);

    hipMemsetAsync(acc, 0, ((size_t)B * 4 + 1) * sizeof(float), stream);

    dim3 grid((A + BLOCK - 1) / BLOCK, B);
    ainno_main<<<grid, BLOCK, 0, stream>>>(ss, anchors, gt, acc, out, A, K, B);
}